// Round 5
// baseline (389.986 us; speedup 1.0000x reference)
//
#include <hip/hip_runtime.h>
#include <hip/hip_fp16.h>

typedef _Float16 half8 __attribute__((ext_vector_type(8)));
typedef _Float16 half4v __attribute__((ext_vector_type(4)));
typedef float f32x4 __attribute__((ext_vector_type(4)));

static constexpr int B_ = 8, T_ = 64, N_ = 256;
static constexpr int F0 = 12, F1 = 64, F2 = 32;
static constexpr int BT_ = B_ * T_;

__device__ inline float tanh_fast(float x) {
    x = fminf(20.f, fmaxf(-20.f, x));
    float e = __expf(2.f * x);
    return (e - 1.f) / (e + 1.f);
}

// ---------------- K0: S (BT,256,256) f32 -> S^T hi/lo fp16 planes ----------
__global__ void k_transpose_s(const float* __restrict__ S,
                              _Float16* __restrict__ STh, _Float16* __restrict__ STl) {
    int bt = blockIdx.x;
    int n0 = blockIdx.y * 64;
    const float* s = S + (size_t)bt * N_ * N_;
    _Float16* sth = STh + (size_t)bt * N_ * N_;
    _Float16* stl = STl + (size_t)bt * N_ * N_;
    __shared__ float tile[64][65];
    int tx = threadIdx.x & 15;
    int ty = threadIdx.x >> 4;
    for (int tm = 0; tm < N_; tm += 64) {
        #pragma unroll
        for (int r = ty; r < 64; r += 32) {
            float4 v = *(const float4*)(s + (size_t)(tm + r) * N_ + n0 + tx * 4);
            tile[r][tx * 4 + 0] = v.x;
            tile[r][tx * 4 + 1] = v.y;
            tile[r][tx * 4 + 2] = v.z;
            tile[r][tx * 4 + 3] = v.w;
        }
        __syncthreads();
        #pragma unroll
        for (int rr = ty; rr < 64; rr += 32) {
            half4v h, l;
            #pragma unroll
            for (int c = 0; c < 4; ++c) {
                float v = tile[tx * 4 + c][rr];
                _Float16 hh = (_Float16)v;
                h[c] = hh;
                l[c] = (_Float16)(v - (float)hh);
            }
            size_t o = (size_t)(n0 + rr) * N_ + tm + tx * 4;
            *(half4v*)(sth + o) = h;
            *(half4v*)(stl + o) = l;
        }
        __syncthreads();
    }
}

// ---------------- K1: U1(b,t) = x(b,t-1) @ S(b,t), x read as f32, split in-reg
__global__ void k_chain1x(const float* __restrict__ x,
                          const _Float16* __restrict__ STh, const _Float16* __restrict__ STl,
                          _Float16* __restrict__ Oh, _Float16* __restrict__ Ol) {
    int bt = blockIdx.x;
    int t = bt & (T_ - 1);
    int wave = threadIdx.x >> 6;
    int lane = threadIdx.x & 63;
    int l15 = lane & 15;
    int lk = lane >> 4;
    int n0 = wave * 64;

    f32x4 acc[4];
    #pragma unroll
    for (int j = 0; j < 4; ++j) acc[j] = (f32x4){0.f, 0.f, 0.f, 0.f};

    if (t > 0) {
        const float* A = x + (size_t)(bt - 1) * F0 * N_;
        const _Float16* B_h = STh + (size_t)bt * N_ * N_;
        const _Float16* B_l = STl + (size_t)bt * N_ * N_;
        #pragma unroll
        for (int kk = 0; kk < 8; ++kk) {
            int kof = kk * 32 + lk * 8;
            half8 ah = {}, al = {};
            if (l15 < F0) {
                const float* ar = A + (size_t)l15 * N_ + kof;
                float4 v0 = *(const float4*)(ar);
                float4 v1 = *(const float4*)(ar + 4);
                float vv[8] = {v0.x, v0.y, v0.z, v0.w, v1.x, v1.y, v1.z, v1.w};
                #pragma unroll
                for (int c = 0; c < 8; ++c) {
                    _Float16 hh = (_Float16)vv[c];
                    ah[c] = hh;
                    al[c] = (_Float16)(vv[c] - (float)hh);
                }
            }
            #pragma unroll
            for (int j = 0; j < 4; ++j) {
                half8 bh = *(const half8*)(B_h + (size_t)(n0 + j * 16 + l15) * N_ + kof);
                half8 bl = *(const half8*)(B_l + (size_t)(n0 + j * 16 + l15) * N_ + kof);
                acc[j] = __builtin_amdgcn_mfma_f32_16x16x32_f16(ah, bh, acc[j], 0, 0, 0);
                acc[j] = __builtin_amdgcn_mfma_f32_16x16x32_f16(al, bh, acc[j], 0, 0, 0);
                acc[j] = __builtin_amdgcn_mfma_f32_16x16x32_f16(ah, bl, acc[j], 0, 0, 0);
            }
        }
    }
    _Float16* O_h = Oh + (size_t)bt * 16 * N_;
    _Float16* O_l = Ol + (size_t)bt * 16 * N_;
    #pragma unroll
    for (int j = 0; j < 4; ++j)
        #pragma unroll
        for (int r = 0; r < 4; ++r) {
            float v = acc[j][r];
            _Float16 h = (_Float16)v;
            size_t idx = (size_t)(lk * 4 + r) * N_ + n0 + j * 16 + l15;
            O_h[idx] = h;
            O_l[idx] = (_Float16)(v - (float)h);
        }
}

// ---------------- K2: V1 = U1(t-1)@S(t); y1 = tanh(b1 + W1 ⋅ [x,U1,V1]) ----
__global__ void k_layer1b(const _Float16* __restrict__ U1h, const _Float16* __restrict__ U1l,
                          const _Float16* __restrict__ STh, const _Float16* __restrict__ STl,
                          const float* __restrict__ x,
                          const float* __restrict__ W1,  // (64,3,12)
                          const float* __restrict__ b1,
                          _Float16* __restrict__ Y1h, _Float16* __restrict__ Y1l) {
    __shared__ float v1s[16][260];
    int bt = blockIdx.x;
    int t = bt & (T_ - 1);
    int wave = threadIdx.x >> 6;
    int lane = threadIdx.x & 63;
    int l15 = lane & 15;
    int lk = lane >> 4;
    int n0 = wave * 64;

    f32x4 acc[4];
    #pragma unroll
    for (int j = 0; j < 4; ++j) acc[j] = (f32x4){0.f, 0.f, 0.f, 0.f};

    if (t > 0) {
        const _Float16* A_h = U1h + (size_t)(bt - 1) * 16 * N_;
        const _Float16* A_l = U1l + (size_t)(bt - 1) * 16 * N_;
        const _Float16* B_h = STh + (size_t)bt * N_ * N_;
        const _Float16* B_l = STl + (size_t)bt * N_ * N_;
        #pragma unroll
        for (int kk = 0; kk < 8; ++kk) {
            int kof = kk * 32 + lk * 8;
            half8 ah = *(const half8*)(A_h + (size_t)l15 * N_ + kof);
            half8 al = *(const half8*)(A_l + (size_t)l15 * N_ + kof);
            #pragma unroll
            for (int j = 0; j < 4; ++j) {
                half8 bh = *(const half8*)(B_h + (size_t)(n0 + j * 16 + l15) * N_ + kof);
                half8 bl = *(const half8*)(B_l + (size_t)(n0 + j * 16 + l15) * N_ + kof);
                acc[j] = __builtin_amdgcn_mfma_f32_16x16x32_f16(ah, bh, acc[j], 0, 0, 0);
                acc[j] = __builtin_amdgcn_mfma_f32_16x16x32_f16(al, bh, acc[j], 0, 0, 0);
                acc[j] = __builtin_amdgcn_mfma_f32_16x16x32_f16(ah, bl, acc[j], 0, 0, 0);
            }
        }
    }
    #pragma unroll
    for (int j = 0; j < 4; ++j)
        #pragma unroll
        for (int r = 0; r < 4; ++r)
            v1s[lk * 4 + r][n0 + j * 16 + l15] = acc[j][r];
    __syncthreads();

    int n = threadIdx.x;
    const float* xc = x + (size_t)bt * F0 * N_;
    const _Float16* u1hc = U1h + (size_t)bt * 16 * N_;
    const _Float16* u1lc = U1l + (size_t)bt * 16 * N_;
    float z0[F0], z1[F0], z2[F0];
    #pragma unroll
    for (int g = 0; g < F0; ++g) {
        z0[g] = xc[(size_t)g * N_ + n];
        z1[g] = (float)u1hc[(size_t)g * N_ + n] + (float)u1lc[(size_t)g * N_ + n];
        z2[g] = v1s[g][n];
    }
    _Float16* yh = Y1h + (size_t)bt * F1 * N_;
    _Float16* yl = Y1l + (size_t)bt * F1 * N_;
    #pragma unroll
    for (int f = 0; f < F1; ++f) {
        float a2 = b1[f];
        const float* w = W1 + f * 36;
        #pragma unroll
        for (int g = 0; g < F0; ++g)
            a2 += w[g] * z0[g] + w[12 + g] * z1[g] + w[24 + g] * z2[g];
        float yv = tanh_fast(a2);
        _Float16 h = (_Float16)yv;
        yh[(size_t)f * N_ + n] = h;
        yl[(size_t)f * N_ + n] = (_Float16)(yv - (float)h);
    }
}

// ---------------- K3: U2(b,t) = Y1(b,t-1) @ S(b,t), split-fp16 (streaming) --
template <int MT>
__global__ void k_chain(const _Float16* __restrict__ Ah, const _Float16* __restrict__ Al,
                        const _Float16* __restrict__ STh, const _Float16* __restrict__ STl,
                        _Float16* __restrict__ Oh, _Float16* __restrict__ Ol) {
    constexpr int M = 16 * MT;
    int bt = blockIdx.x;
    int t = bt & (T_ - 1);
    int wave = threadIdx.x >> 6;
    int lane = threadIdx.x & 63;
    int l15 = lane & 15;
    int lk = lane >> 4;
    int n0 = wave * 64;

    f32x4 acc[MT][4];
    #pragma unroll
    for (int i = 0; i < MT; ++i)
        #pragma unroll
        for (int j = 0; j < 4; ++j)
            acc[i][j] = (f32x4){0.f, 0.f, 0.f, 0.f};

    if (t > 0) {
        const _Float16* A_h = Ah + (size_t)(bt - 1) * M * N_;
        const _Float16* A_l = Al + (size_t)(bt - 1) * M * N_;
        const _Float16* B_h = STh + (size_t)bt * N_ * N_;
        const _Float16* B_l = STl + (size_t)bt * N_ * N_;
        #pragma unroll
        for (int kk = 0; kk < 8; ++kk) {
            int kof = kk * 32 + lk * 8;
            half8 ah[MT], al[MT];
            #pragma unroll
            for (int i = 0; i < MT; ++i) {
                ah[i] = *(const half8*)(A_h + (size_t)(i * 16 + l15) * N_ + kof);
                al[i] = *(const half8*)(A_l + (size_t)(i * 16 + l15) * N_ + kof);
            }
            #pragma unroll
            for (int j = 0; j < 4; ++j) {
                half8 bh = *(const half8*)(B_h + (size_t)(n0 + j * 16 + l15) * N_ + kof);
                half8 bl = *(const half8*)(B_l + (size_t)(n0 + j * 16 + l15) * N_ + kof);
                #pragma unroll
                for (int i = 0; i < MT; ++i) {
                    acc[i][j] = __builtin_amdgcn_mfma_f32_16x16x32_f16(ah[i], bh, acc[i][j], 0, 0, 0);
                    acc[i][j] = __builtin_amdgcn_mfma_f32_16x16x32_f16(al[i], bh, acc[i][j], 0, 0, 0);
                    acc[i][j] = __builtin_amdgcn_mfma_f32_16x16x32_f16(ah[i], bl, acc[i][j], 0, 0, 0);
                }
            }
        }
    }
    _Float16* O_h = Oh + (size_t)bt * M * N_;
    _Float16* O_l = Ol + (size_t)bt * M * N_;
    #pragma unroll
    for (int i = 0; i < MT; ++i)
        #pragma unroll
        for (int j = 0; j < 4; ++j)
            #pragma unroll
            for (int r = 0; r < 4; ++r) {
                float v = acc[i][j][r];
                _Float16 h = (_Float16)v;
                size_t idx = (size_t)(i * 16 + lk * 4 + r) * N_ + n0 + j * 16 + l15;
                O_h[idx] = h;
                O_l[idx] = (_Float16)(v - (float)h);
            }
}

// ---------------- K4: V2(b,t) = U2(b,t-1) @ S(b,t), f32 output (streaming) --
__global__ void k_chainV2f(const _Float16* __restrict__ Ah, const _Float16* __restrict__ Al,
                           const _Float16* __restrict__ STh, const _Float16* __restrict__ STl,
                           float* __restrict__ O) {
    int bt = blockIdx.x;
    int t = bt & (T_ - 1);
    int wave = threadIdx.x >> 6;
    int lane = threadIdx.x & 63;
    int l15 = lane & 15;
    int lk = lane >> 4;
    int n0 = wave * 64;

    f32x4 acc[4][4];
    #pragma unroll
    for (int i = 0; i < 4; ++i)
        #pragma unroll
        for (int j = 0; j < 4; ++j)
            acc[i][j] = (f32x4){0.f, 0.f, 0.f, 0.f};

    if (t > 0) {
        const _Float16* A_h = Ah + (size_t)(bt - 1) * 64 * N_;
        const _Float16* A_l = Al + (size_t)(bt - 1) * 64 * N_;
        const _Float16* B_h = STh + (size_t)bt * N_ * N_;
        const _Float16* B_l = STl + (size_t)bt * N_ * N_;
        #pragma unroll
        for (int kk = 0; kk < 8; ++kk) {
            int kof = kk * 32 + lk * 8;
            half8 ah[4], al[4];
            #pragma unroll
            for (int i = 0; i < 4; ++i) {
                ah[i] = *(const half8*)(A_h + (size_t)(i * 16 + l15) * N_ + kof);
                al[i] = *(const half8*)(A_l + (size_t)(i * 16 + l15) * N_ + kof);
            }
            #pragma unroll
            for (int j = 0; j < 4; ++j) {
                half8 bh = *(const half8*)(B_h + (size_t)(n0 + j * 16 + l15) * N_ + kof);
                half8 bl = *(const half8*)(B_l + (size_t)(n0 + j * 16 + l15) * N_ + kof);
                #pragma unroll
                for (int i = 0; i < 4; ++i) {
                    acc[i][j] = __builtin_amdgcn_mfma_f32_16x16x32_f16(ah[i], bh, acc[i][j], 0, 0, 0);
                    acc[i][j] = __builtin_amdgcn_mfma_f32_16x16x32_f16(al[i], bh, acc[i][j], 0, 0, 0);
                    acc[i][j] = __builtin_amdgcn_mfma_f32_16x16x32_f16(ah[i], bl, acc[i][j], 0, 0, 0);
                }
            }
        }
    }
    float* Ob = O + (size_t)bt * 64 * N_;
    #pragma unroll
    for (int i = 0; i < 4; ++i)
        #pragma unroll
        for (int j = 0; j < 4; ++j)
            #pragma unroll
            for (int r = 0; r < 4; ++r)
                Ob[(size_t)(i * 16 + lk * 4 + r) * N_ + n0 + j * 16 + l15] = acc[i][j][r];
}

// ---------------- K5: per-column combine + readout --------------------------
// y2 = tanh(b2 + W2.[Y1(t), U2(t), V2(t)]); h = tanh(A1 y2 + c1); out = A2 h + c2
__global__ void k_combine2(const _Float16* __restrict__ Y1h, const _Float16* __restrict__ Y1l,
                           const _Float16* __restrict__ U2h, const _Float16* __restrict__ U2l,
                           const float* __restrict__ V2,
                           const float* __restrict__ W2, const float* __restrict__ b2,
                           const float* __restrict__ A1, const float* __restrict__ c1,
                           const float* __restrict__ A2, const float* __restrict__ c2,
                           float* __restrict__ out) {
    __shared__ float lw[F2 * 192];      // 24 KB
    __shared__ float la1[32 * 32];      // 4 KB
    int bt = blockIdx.x;
    int n = blockIdx.y * 128 + threadIdx.x;
    for (int i = threadIdx.x; i < F2 * 192; i += 128) lw[i] = W2[i];
    for (int i = threadIdx.x; i < 32 * 32; i += 128) la1[i] = A1[i];
    __syncthreads();

    const _Float16* yh = Y1h + (size_t)bt * 64 * N_;
    const _Float16* yl = Y1l + (size_t)bt * 64 * N_;
    const _Float16* uh = U2h + (size_t)bt * 64 * N_;
    const _Float16* ul = U2l + (size_t)bt * 64 * N_;
    const float*    vv = V2  + (size_t)bt * 64 * N_;

    float y2[F2];
    #pragma unroll
    for (int f = 0; f < F2; ++f) y2[f] = b2[f];

    for (int g = 0; g < 64; ++g) {
        size_t o = (size_t)g * N_ + n;
        float zy = (float)yh[o] + (float)yl[o];
        float zu = (float)uh[o] + (float)ul[o];
        float zv = vv[o];
        const float* w = lw + g;
        #pragma unroll
        for (int f = 0; f < F2; ++f)
            y2[f] += w[f * 192] * zy + w[f * 192 + 64] * zu + w[f * 192 + 128] * zv;
    }
    #pragma unroll
    for (int f = 0; f < F2; ++f) y2[f] = tanh_fast(y2[f]);

    float o0 = 0.f, o1 = 0.f;
    #pragma unroll
    for (int j = 0; j < 32; ++j) {
        const float* a1 = la1 + j * 32;
        float s = c1[j];
        #pragma unroll
        for (int f = 0; f < 32; ++f) s += a1[f] * y2[f];
        float hj = tanh_fast(s);
        o0 += A2[j] * hj;
        o1 += A2[32 + j] * hj;
    }
    out[((size_t)bt * 2 + 0) * N_ + n] = o0 + c2[0];
    out[((size_t)bt * 2 + 1) * N_ + n] = o1 + c2[1];
}

extern "C" void kernel_launch(void* const* d_in, const int* in_sizes, int n_in,
                              void* d_out, int out_size, void* d_ws, size_t ws_size,
                              hipStream_t stream) {
    const float* x  = (const float*)d_in[0];
    const float* S  = (const float*)d_in[1];
    const float* W1 = (const float*)d_in[2];
    const float* b1 = (const float*)d_in[3];
    const float* W2 = (const float*)d_in[4];
    const float* b2 = (const float*)d_in[5];
    const float* A1 = (const float*)d_in[6];
    const float* c1 = (const float*)d_in[7];
    const float* A2 = (const float*)d_in[8];
    const float* c2 = (const float*)d_in[9];
    float* out = (float*)d_out;

    char* ws = (char*)d_ws;
    const size_t SZ_ST = (size_t)BT_ * N_ * N_ * 2;   // 67,108,864 per plane
    const size_t SZ_U1 = (size_t)BT_ * 16 * N_ * 2;   //  4,194,304 per plane
    const size_t SZ_Y1 = (size_t)BT_ * 64 * N_ * 2;   // 16,777,216 per plane
    const size_t SZ_V2 = (size_t)BT_ * 64 * N_ * 4;   // 33,554,432 (f32)
    // layout: [STh][STl][Y1h][Y1l][U2h][U2l][V2]; U1 nests inside V2 region
    // (U1 dead after k_layer1b; V2 written later by k_chainV2f).
    size_t off = 0;
    _Float16* STh = (_Float16*)(ws + off); off += SZ_ST;
    _Float16* STl = (_Float16*)(ws + off); off += SZ_ST;
    _Float16* Y1h = (_Float16*)(ws + off); off += SZ_Y1;
    _Float16* Y1l = (_Float16*)(ws + off); off += SZ_Y1;
    _Float16* U2h = (_Float16*)(ws + off); off += SZ_Y1;
    _Float16* U2l = (_Float16*)(ws + off); off += SZ_Y1;
    float*    V2  = (float*)(ws + off);
    _Float16* U1h = (_Float16*)(ws + off); off += SZ_U1;
    _Float16* U1l = (_Float16*)(ws + off); off += SZ_U1;
    off = off - 2 * SZ_U1 + SZ_V2;
    if (ws_size < off) return;  // insufficient scratch -> clean failure

    k_transpose_s<<<dim3(BT_, 4), 512, 0, stream>>>(S, STh, STl);
    k_chain1x<<<BT_, 256, 0, stream>>>(x, STh, STl, U1h, U1l);
    k_layer1b<<<BT_, 256, 0, stream>>>(U1h, U1l, STh, STl, x, W1, b1, Y1h, Y1l);
    k_chain<4><<<BT_, 256, 0, stream>>>(Y1h, Y1l, STh, STl, U2h, U2l);
    k_chainV2f<<<BT_, 256, 0, stream>>>(U2h, U2l, STh, STl, V2);
    k_combine2<<<dim3(BT_, 2), 128, 0, stream>>>(Y1h, Y1l, U2h, U2l, V2,
                                                 W2, b2, A1, c1, A2, c2, out);
}